// Round 1
// 255.770 us; speedup vs baseline: 1.0227x; 1.0227x over previous
//
#include <hip/hip_runtime.h>

typedef unsigned short ushort_t;
typedef unsigned int uint_t;
typedef __attribute__((ext_vector_type(8))) _Float16 f16x8;
typedef __attribute__((ext_vector_type(4))) float floatx4;

#define ZDIM 32
#define KDIM 4
#define HDIM 128
#define B_TOTAL 32768
#define TB 32

// ws layout (ushort element offsets): Wd fp16 [k][n][c], Wsm fp16 [m][n][c]
#define WS_WD16 0            // 4*1024*128 = 524288
#define WS_SM16 524288       // 3*128*128 = 49152

// LDS layout (byte offsets). D fp16: [batch][i][j] at batch*1096 + i*34 + j
// (ushort units). Batch pitch 1096 => 548 words == 4 mod 32.
#define D_ROW   34
#define D_BP    1096
#define SH_D_OFF  0          // ushort[32][1096] = 70144 B
#define AUX_PITCH 132
#define SH_AUX_OFF 0         // float [3][32][132] = 50688 B (pre-loop, aliases D)
#define SH_H_OFF  50688      // half [32][136] = 8704 B (pre-loop, aliases D; end 59392)
#define SH_Z_OFF  70144      // float [32][36] = 4608 B
#define SH_T_OFF  74752      // float [32][36] = 4608 B
#define LDS_BYTES 79360      // x2 = 158720 <= 160 KiB -> 2 WGs/CU

__device__ __forceinline__ float fast_tanh(float x) {
    float e = __expf(2.0f * x);
    return 1.0f - 2.0f / (e + 1.0f);
}
__device__ __forceinline__ float f16lo(uint_t v) {
    return (float)__builtin_bit_cast(_Float16, (ushort_t)(v & 0xFFFFu));
}
__device__ __forceinline__ float f16hi(uint_t v) {
    return (float)__builtin_bit_cast(_Float16, (ushort_t)(v >> 16));
}
__device__ __forceinline__ ushort_t f2h(float x) {
    return __builtin_bit_cast(ushort_t, (_Float16)x);
}
__device__ __forceinline__ ushort4 cvt4(float4 v) {
    ushort4 o; o.x = f2h(v.x); o.y = f2h(v.y); o.z = f2h(v.z); o.w = f2h(v.w);
    return o;
}
// pack 4 floats into 2 dwords of fp16 (kk folds at compile time under unroll)
__device__ __forceinline__ uint2 packq(float4 v) {
    uint2 r;
    r.x = (uint_t)f2h(v.x) | ((uint_t)f2h(v.y) << 16);
    r.y = (uint_t)f2h(v.z) | ((uint_t)f2h(v.w) << 16);
    return r;
}
__device__ __forceinline__ float half_at(uint2 q, int kk) {
    uint_t w = (kk & 2) ? q.y : q.x;
    return (kk & 1) ? f16hi(w) : f16lo(w);
}

// ---------------------------------------------------------------------------
// Kernel 1: convert Wd (reordered per-k-slice) and Wd1/Wd2/Wb to fp16.
// ---------------------------------------------------------------------------
__global__ __launch_bounds__(256) void convert_kernel(
    const float* __restrict__ Wd, const float* __restrict__ Wd1,
    const float* __restrict__ Wd2, const float* __restrict__ Wb,
    ushort_t* __restrict__ ws)
{
    int g = blockIdx.x * 256 + threadIdx.x;
    if (g < 131072) {
        int k = g >> 15;            // 32768 float4 per k-slice
        int rem = g & 32767;
        int n = rem >> 5;           // n = i*32+j
        int c4 = rem & 31;
        float4 v = *((const float4*)Wd + (size_t)(4 * n + k) * 32 + c4);
        ((ushort4*)(ws + WS_WD16))[g] = cvt4(v);
    } else {
        int s = g - 131072;         // [0, 12288)
        const float* src = (s < 4096) ? Wd1 : ((s < 8192) ? Wd2 : Wb);
        int r = s & 4095;
        float4 v = ((const float4*)src)[r];
        ((ushort4*)(ws + WS_SM16))[s] = cvt4(v);
    }
}

// ---------------------------------------------------------------------------
// Kernel 2: fused fp16 encoder GEMMs + K-step flow. TB=32 batches/WG.
// Round-13 change vs round 12: same per-WG work repartitioned across 512
// threads (8 waves) instead of 256 (4 waves). LDS footprint unchanged
// (79.4 KB x 2 WGs = 158.7 KB <= 160 KiB), so still 2 WGs/CU, but now
// 16 waves/CU (4/SIMD) instead of 8 -- counters showed latency-bound
// (MfmaUtil 8%, VALUBusy 16%, Occupancy 22%): doubling resident waves
// halves every barrier-separated phase's critical path and doubles the
// scheduler's latency-hiding pool. Column partition of the 1024-col
// k-slice is exact over 8 waves (no duplicate B reads); flow uses 16
// threads/batch (2 columns each) instead of 8 (4 columns).
// __launch_bounds__(512, 4) -> 128 arch regs (proven budget).
// ---------------------------------------------------------------------------
__global__ __launch_bounds__(512, 4) void sylv_kernel(
    const ushort_t* __restrict__ wsb,
    const float* __restrict__ hglob,
    const float* __restrict__ z0,
    const float* __restrict__ bd,
    const float* __restrict__ bd1,
    const float* __restrict__ bd2,
    const float* __restrict__ bb,
    float* __restrict__ out)
{
    extern __shared__ char smem[];
    _Float16* Dh     = (_Float16*)(smem + SH_D_OFF);
    float*    sh_aux = (float*)(smem + SH_AUX_OFF);
    _Float16* sh_h   = (_Float16*)(smem + SH_H_OFF);
    float*    sh_z   = (float*)(smem + SH_Z_OFF);
    float*    sh_t   = (float*)(smem + SH_T_OFF);

    const int t   = threadIdx.x;
    const int bg0 = blockIdx.x * TB;
    const int lane = t & 63, w = t >> 6;    // w = 0..7 = column group
    const int l15 = lane & 15, l4 = lane >> 4;
    // flow mapping: 16 threads per batch; thread handles j in {j3, j3+16}
    const int j3 = t & 15;
    const int fb = t >> 4;          // 0..31

    // ---- stage h (fp32 -> fp16 in LDS) and z0 ----
    {
        const float4* hsrc = (const float4*)(hglob + (size_t)bg0 * HDIM);
        #pragma unroll
        for (int it = 0; it < 2; ++it) {
            int c = t + it * 512;       // 1024 float4 chunks
            int row = c >> 5, col4 = c & 31;
            float4 v = hsrc[c];
            *(ushort4*)((ushort_t*)sh_h + row * 136 + col4 * 4) = cvt4(v);
        }
        float2 zv = *(const float2*)(z0 + (size_t)(bg0 + fb) * ZDIM + j3 * 2);
        *(float2*)(sh_z + fb * 36 + j3 * 2) = zv;
    }
    __syncthreads();

    // ---- A fragments: TWO 16-row tiles (rows 0..31), same for all waves ----
    f16x8 ah[2][4];
    #pragma unroll
    for (int mt = 0; mt < 2; ++mt)
        #pragma unroll
        for (int kc = 0; kc < 4; ++kc)
            ah[mt][kc] = *(const f16x8*)(sh_h + (mt * 16 + l15) * 136 + kc * 32 + l4 * 8);

    // ---- small GEMMs (fp16): d1, d2, bpre -> aux[m][batch][n] ----
    // 24 (m,ntile) jobs over 8 waves; each wave does both row-tiles.
    #pragma unroll
    for (int pi = 0; pi < 3; ++pi) {
        int p = w * 3 + pi;             // [0,24)
        int m_i = p >> 3, nt = p & 7, n = nt * 16 + l15;
        const _Float16* wp = (const _Float16*)(wsb + WS_SM16) + (size_t)(m_i * 128 + n) * 128 + l4 * 8;
        floatx4 a0 = {0.f, 0.f, 0.f, 0.f}, a1 = {0.f, 0.f, 0.f, 0.f};
        #pragma unroll
        for (int kc = 0; kc < 4; ++kc) {
            f16x8 bh = *(const f16x8*)(wp + kc * 32);
            a0 = __builtin_amdgcn_mfma_f32_16x16x32_f16(ah[0][kc], bh, a0, 0, 0, 0);
            a1 = __builtin_amdgcn_mfma_f32_16x16x32_f16(ah[1][kc], bh, a1, 0, 0, 0);
        }
        const float* bv = (m_i == 0) ? bd1 : ((m_i == 1) ? bd2 : bb);
        float bias = bv[n];
        float* ap = sh_aux + m_i * (32 * AUX_PITCH) + n;
        #pragma unroll
        for (int r = 0; r < 4; ++r) {
            float v0 = a0[r] + bias, v1 = a1[r] + bias;
            if (m_i < 2) { v0 = fast_tanh(v0); v1 = fast_tanh(v1); }
            ap[(l4 * 4 + r) * AUX_PITCH] = v0;
            ap[(16 + l4 * 4 + r) * AUX_PITCH] = v1;
        }
    }
    __syncthreads();

    // ---- aux -> 12 packed-fp16 dwords/thread, then free the D region ----
    uint2 d1q[2], d2q[2], bpq[2];
    #pragma unroll
    for (int q = 0; q < 2; ++q) {
        int joff = (j3 + 16 * q) * 4;
        d1q[q] = packq(*(const float4*)(sh_aux + 0 * (32 * AUX_PITCH) + fb * AUX_PITCH + joff));
        d2q[q] = packq(*(const float4*)(sh_aux + 1 * (32 * AUX_PITCH) + fb * AUX_PITCH + joff));
        bpq[q] = packq(*(const float4*)(sh_aux + 2 * (32 * AUX_PITCH) + fb * AUX_PITCH + joff));
    }
    __syncthreads();

    float ld_acc = 0.f;
    const _Float16* Db  = Dh + fb * D_BP;       // this thread's batch row
    const _Float16* Dbp = Db + j3;              // pre-phase base (imm offsets)
    const uint_t*   Dbw = (const uint_t*)Db + j3 * 17;  // dz-phase base

    #pragma unroll
    for (int kk = 0; kk < KDIM; ++kk) {
        // ---- GEMM: D_k[b][n] = h@Wd_k^T + bd (fp16 in, fp32 acc) ----
        const _Float16* wdk = (const _Float16*)(wsb + WS_WD16) + (size_t)kk * 131072;
        #pragma unroll
        for (int g = 0; g < 8; ++g) {
            int nc = w * 128 + g * 16 + l15;
            const _Float16* w0 = wdk + (size_t)nc * 128 + l4 * 8;
            floatx4 a0 = {0.f,0.f,0.f,0.f}, a1 = {0.f,0.f,0.f,0.f};
            #pragma unroll
            for (int kc = 0; kc < 4; ++kc) {
                f16x8 b0 = *(const f16x8*)(w0 + kc * 32);
                a0 = __builtin_amdgcn_mfma_f32_16x16x32_f16(ah[0][kc], b0, a0, 0, 0, 0);
                a1 = __builtin_amdgcn_mfma_f32_16x16x32_f16(ah[1][kc], b0, a1, 0, 0, 0);
            }
            int ii = nc >> 5;
            int base = ii * D_ROW + (nc & 31);
            float bias0 = bd[4 * nc + kk];
            #pragma unroll
            for (int r = 0; r < 4; ++r) {
                Dh[(l4 * 4 + r) * D_BP + base]      = (_Float16)(a0[r] + bias0);
                Dh[(16 + l4 * 4 + r) * D_BP + base] = (_Float16)(a1[r] + bias0);
            }
        }
        __syncthreads();

        // ---- pre[j] = b[j] + z_per[j]*d2[j] + sum_{i>j} z_per[i]*D[i,j] ----
        const bool flip = (kk & 1) != 0;
        float s[2];
        #pragma unroll
        for (int q = 0; q < 2; ++q) {
            int j = j3 + 16 * q;
            int zidx = flip ? (31 - j) : j;
            s[q] = half_at(bpq[q], kk) + sh_z[fb * 36 + zidx] * half_at(d2q[q], kk);
        }
        #pragma unroll
        for (int i = 1; i < 32; ++i) {
            float zi = sh_z[fb * 36 + (flip ? (31 - i) : i)];
            #pragma unroll
            for (int q = 0; q < 2; ++q) {
                if (i > 16 * q) {       // j = j3+16q >= 16q: i <= 16q never contributes
                    float dd = (float)Dbp[i * D_ROW + 16 * q];
                    float m = (i >= 16 * q + 16) ? zi : ((i > j3 + 16 * q) ? zi : 0.0f);
                    s[q] = fmaf(dd, m, s[q]);
                }
            }
        }
        float tq[2];
        #pragma unroll
        for (int q = 0; q < 2; ++q) {
            int j = j3 + 16 * q;
            float tt = fast_tanh(s[q]);
            tq[q] = tt;
            sh_t[fb * 36 + j] = tt;
            float d1 = half_at(d1q[q], kk), d2 = half_at(d2q[q], kk);
            float dj = (1.f - tt * tt) * (d1 * d2) + 1.f;
            ld_acc += __logf(fabsf(dj));
        }
        // barrier protects the sh_t hand-off (round-9 flake lesson)
        __syncthreads();

        // ---- dz[p] = t[p]*d1[p] + sum_{j>p} t[j]*D[p,j]; z update ----
        float dzv[2];
        #pragma unroll
        for (int q = 0; q < 2; ++q)
            dzv[q] = tq[q] * half_at(d1q[q], kk);
        #pragma unroll
        for (int w2 = 0; w2 < 16; ++w2) {
            int j0 = 2 * w2;
            float tl = sh_t[fb * 36 + j0];
            float th = sh_t[fb * 36 + j0 + 1];
            #pragma unroll
            for (int q = 0; q < 2; ++q) {
                if (w2 >= 8 * q) {              // j <= 16q-1 < p never contributes
                    uint_t v = Dbw[272 * q + w2];   // row (j3+16q), word w2
                    if (w2 >= 8 * q + 8) {      // all j >= 16q+16 > p
                        dzv[q] = fmaf(f16lo(v), tl, dzv[q]);
                        dzv[q] = fmaf(f16hi(v), th, dzv[q]);
                    } else {
                        dzv[q] = fmaf(f16lo(v), (j0 > j3 + 16 * q) ? tl : 0.f, dzv[q]);
                        dzv[q] = fmaf(f16hi(v), (j0 + 1 > j3 + 16 * q) ? th : 0.f, dzv[q]);
                    }
                }
            }
        }
        #pragma unroll
        for (int q = 0; q < 2; ++q) {
            int j = j3 + 16 * q;
            int zidx = flip ? (31 - j) : j;
            sh_z[fb * 36 + zidx] += dzv[q];
        }
        __syncthreads();
    }

    // ---- epilogue: write z and log_det_j ----
    {
        float2 zv = *(const float2*)(sh_z + fb * 36 + j3 * 2);
        *(float2*)(out + (size_t)(bg0 + fb) * ZDIM + j3 * 2) = zv;
        float v = ld_acc;
        v += __shfl_xor(v, 1, 16);
        v += __shfl_xor(v, 2, 16);
        v += __shfl_xor(v, 4, 16);
        v += __shfl_xor(v, 8, 16);
        if (j3 == 0) out[(size_t)B_TOTAL * ZDIM + bg0 + fb] = v;
    }
}

extern "C" void kernel_launch(void* const* d_in, const int* in_sizes, int n_in,
                              void* d_out, int out_size, void* d_ws, size_t ws_size,
                              hipStream_t stream) {
    const float* z0  = (const float*)d_in[0];
    const float* h   = (const float*)d_in[1];
    const float* Wd  = (const float*)d_in[2];
    const float* bd  = (const float*)d_in[3];
    const float* Wd1 = (const float*)d_in[4];
    const float* bd1 = (const float*)d_in[5];
    const float* Wd2 = (const float*)d_in[6];
    const float* bd2 = (const float*)d_in[7];
    const float* Wb  = (const float*)d_in[8];
    const float* bb  = (const float*)d_in[9];
    ushort_t* ws = (ushort_t*)d_ws;
    float* out = (float*)d_out;

    convert_kernel<<<560, 256, 0, stream>>>(Wd, Wd1, Wd2, Wb, ws);

    (void)hipFuncSetAttribute((const void*)sylv_kernel,
                              hipFuncAttributeMaxDynamicSharedMemorySize, LDS_BYTES);
    sylv_kernel<<<B_TOTAL / TB, 512, LDS_BYTES, stream>>>(ws, h, z0, bd, bd1, bd2, bb, out);
}